// Round 4
// baseline (394.153 us; speedup 1.0000x reference)
//
#include <hip/hip_runtime.h>

#define KTAPS 9
#define DIL 6
#define BN_EPS 1e-5f
#define BB 8
#define CIN 256
#define COUT 256
#define NPTS 8192
#define BN 128
#define NCHUNK 72      // 2304 / 32
#define BSTRIDE 40     // B_lds row stride (elems); 80 B keeps b128 phases spread

typedef __attribute__((ext_vector_type(8))) short short8;
typedef __attribute__((ext_vector_type(4))) float f32x4;

__device__ __forceinline__ unsigned short f2bf(float f) {
  union { float f; unsigned u; } v; v.f = f;
  unsigned r = v.u + 0x7fffu + ((v.u >> 16) & 1u);   // RNE
  return (unsigned short)(r >> 16);
}

// ---------------------------------------------------------------- pre: pack W + zero sums
// Wa[chunk][mi][kk]; chunk = ktap*8 + c8; element = W[mi][c8*32+kk][ktap]
__global__ __launch_bounds__(256)
void pre_kernel(const float* __restrict__ W, short* __restrict__ Wa,
                float* __restrict__ sums) {
  int bid = blockIdx.x;
  if (bid < 2304) {
    int idx = bid * 256 + threadIdx.x;
    int kk = idx & 31;
    int mi = (idx >> 5) & 255;
    int chunk = idx >> 13;
    int ktap = chunk >> 3;
    int c = ((chunk & 7) << 5) + kk;
    Wa[idx] = (short)f2bf(W[(size_t)mi * (CIN * KTAPS) + c * KTAPS + ktap]);
  } else {
    if (threadIdx.x < 512) sums[threadIdx.x] = 0.f;
  }
}

// ---------------------------------------------------------------- MFMA conv (reg-A, XCD-swizzled)
__global__ __launch_bounds__(256, 2)
void conv_mfma(const float* __restrict__ x, const float* __restrict__ coords,
               const float* __restrict__ rot, const float* __restrict__ dist,
               const short* __restrict__ Wa, const float* __restrict__ bias,
               float* __restrict__ out,
               float* __restrict__ sums1, float* __restrict__ sums2) {
  __shared__ short B_lds[2][BN * BSTRIDE];   // 20 KB
  __shared__ float g_lds[KTAPS * BN];        // 4.6 KB

  const int tid = threadIdx.x;
  // XCD swizzle: batch b -> XCD b (blocks round-robin over 8 XCDs by id)
  const int b = blockIdx.x & 7;
  const int tile = blockIdx.x >> 3;          // 0..63
  const int n0 = tile * BN;

  const int wave = tid >> 6;
  const int lane = tid & 63;
  const int col = lane & 15;
  const int quad = lane >> 4;

  // ---- g prologue: tap weights for this block's 128 n, all 9 taps
  {
    const float* cb = coords + (size_t)b * 3 * NPTS;
    const float* rb = rot + (size_t)b * 3 * NPTS;
    const float* db = dist + (size_t)b * NPTS;
    for (int t = tid; t < KTAPS * BN; t += 256) {
      int k = t >> 7;
      int n = n0 + (t & 127);
      int j = n + (k - KTAPS / 2) * DIL;
      float gv = 0.f;
      if (j >= 0 && j < NPTS) {
        float c0x = cb[n], c0y = cb[NPTS + n], c0z = cb[2 * NPTS + n];
        float r0x = rb[n], r0y = rb[NPTS + n], r0z = rb[2 * NPTS + n];
        float dcx = c0x - cb[j], dcy = c0y - cb[NPTS + j], dcz = c0z - cb[2 * NPTS + j];
        float dc = dcx * dcx + dcy * dcy + dcz * dcz;
        float dd = db[n] - db[j];
        dd *= dd;
        float gauss = expf(-(dc + dd) * 0.5f);
        float rjx = rb[j], rjy = rb[NPTS + j], rjz = rb[2 * NPTS + j];
        float num = r0x * rjx + r0y * rjy + r0z * rjz;
        float r0n = r0x * r0x + r0y * r0y + r0z * r0z;
        float den = sqrtf(r0n * (rjx * rjx + rjy * rjy + rjz * rjz)) + 1e-8f;
        gv = gauss * fabsf(num / den);
      }
      g_lds[t] = gv;
    }
  }

  // staging mapping: 2 n x 8 kk per thread
  const int tl = tid & 63;                   // n-pair index (n = 2*tl, 2*tl+1)
  const int tkk = (tid >> 6) * 8;            // kk base
  const float* xb = x + (size_t)b * CIN * NPTS;
  const short* pA = Wa + ((size_t)(wave * 64 + col) * 32 + quad * 8);

  __syncthreads();   // g_lds ready

  short8 af[2][4];
  float2 xv[8];
  float2 gv;

  // ---- prologue: chunk 0 (k=0 -> off=-24, c8=0): x load, af load, pack B0
  {
    int jn = n0 + 2 * tl - 24;
    bool valid = (jn >= 0) && (jn < NPTS);
    int jnc = valid ? jn : (jn < 0 ? 0 : NPTS - 2);
    const float* px = xb + (size_t)tkk * NPTS + jnc;
#pragma unroll
    for (int cc = 0; cc < 8; ++cc) {
      float2 v = *(const float2*)&px[(size_t)cc * NPTS];
      xv[cc] = valid ? v : make_float2(0.f, 0.f);
    }
#pragma unroll
    for (int m = 0; m < 4; ++m)
      af[0][m] = *(const short8*)&pA[m * 512];
    gv = *(const float2*)&g_lds[2 * tl];
    short8 p0, p1;
#pragma unroll
    for (int cc = 0; cc < 8; ++cc) {
      p0[cc] = (short)f2bf(xv[cc].x * gv.x);
      p1[cc] = (short)f2bf(xv[cc].y * gv.y);
    }
    *(short8*)&B_lds[0][(2 * tl) * BSTRIDE + tkk] = p0;
    *(short8*)&B_lds[0][(2 * tl + 1) * BSTRIDE + tkk] = p1;
  }
  __syncthreads();

  f32x4 acc[4][8];
#pragma unroll
  for (int m = 0; m < 4; ++m)
#pragma unroll
    for (int j = 0; j < 8; ++j) acc[m][j] = (f32x4)0.f;

#pragma unroll 2
  for (int i = 0; i < NCHUNK; ++i) {
    const int cur = i & 1;
    const int nxt = cur ^ 1;
    const bool more = (i + 1) < NCHUNK;

    // ---- prefetch chunk i+1: x into regs, A-frags into regs, g from LDS
    if (more) {
      const int i1 = i + 1;
      const int k1 = i1 >> 3;
      const int c81 = i1 & 7;
      int jn = n0 + 2 * tl + (k1 - 4) * DIL;
      bool valid = (jn >= 0) && (jn < NPTS);
      int jnc = valid ? jn : (jn < 0 ? 0 : NPTS - 2);
      const float* px = xb + (size_t)(c81 * 32 + tkk) * NPTS + jnc;
#pragma unroll
      for (int cc = 0; cc < 8; ++cc) {
        float2 v = *(const float2*)&px[(size_t)cc * NPTS];
        xv[cc] = valid ? v : make_float2(0.f, 0.f);
      }
      const short* pAi = pA + (size_t)i1 * 8192;
#pragma unroll
      for (int m = 0; m < 4; ++m)
        af[nxt][m] = *(const short8*)&pAi[m * 512];
      gv = *(const float2*)&g_lds[k1 * BN + 2 * tl];
    }

    // ---- MFMA on B(cur) + af(cur)
#pragma unroll
    for (int j = 0; j < 8; ++j) {
      short8 bfv = *(short8*)&B_lds[cur][(j * 16 + col) * BSTRIDE + quad * 8];
#pragma unroll
      for (int m = 0; m < 4; ++m)
        acc[m][j] = __builtin_amdgcn_mfma_f32_16x16x32_bf16(af[cur][m], bfv, acc[m][j], 0, 0, 0);
    }

    // ---- pack + stage B(i+1)
    if (more) {
      short8 p0, p1;
#pragma unroll
      for (int cc = 0; cc < 8; ++cc) {
        p0[cc] = (short)f2bf(xv[cc].x * gv.x);
        p1[cc] = (short)f2bf(xv[cc].y * gv.y);
      }
      *(short8*)&B_lds[nxt][(2 * tl) * BSTRIDE + tkk] = p0;
      *(short8*)&B_lds[nxt][(2 * tl + 1) * BSTRIDE + tkk] = p1;
    }
    __syncthreads();
  }

  // ---- epilogue: bias, BN partial sums, store
  const int obase = wave * 64;
  float* outp = out + (size_t)b * COUT * NPTS + n0;
#pragma unroll
  for (int m = 0; m < 4; ++m) {
    const int o0 = obase + m * 16 + quad * 4;
    const float4 bv = *(const float4*)&bias[o0];
#pragma unroll
    for (int j = 0; j < 8; ++j) {
      acc[m][j][0] += bv.x; acc[m][j][1] += bv.y;
      acc[m][j][2] += bv.z; acc[m][j][3] += bv.w;
    }
#pragma unroll
    for (int r = 0; r < 4; ++r) {
      float s1 = 0.f, s2 = 0.f;
#pragma unroll
      for (int j = 0; j < 8; ++j) {
        float v = acc[m][j][r];
        s1 += v; s2 += v * v;
      }
      s1 += __shfl_xor(s1, 1); s2 += __shfl_xor(s2, 1);
      s1 += __shfl_xor(s1, 2); s2 += __shfl_xor(s2, 2);
      s1 += __shfl_xor(s1, 4); s2 += __shfl_xor(s2, 4);
      s1 += __shfl_xor(s1, 8); s2 += __shfl_xor(s2, 8);
      if (col == 0) {
        atomicAdd(&sums1[o0 + r], s1);
        atomicAdd(&sums2[o0 + r], s2);
      }
#pragma unroll
      for (int j = 0; j < 8; ++j)
        outp[(size_t)(o0 + r) * NPTS + j * 16 + col] = acc[m][j][r];
    }
  }
}

// ---------------------------------------------------------------- BN + ReLU
__global__ __launch_bounds__(256)
void bn_apply(float* __restrict__ out, const float* __restrict__ sums1,
              const float* __restrict__ sums2, const float* __restrict__ gamma,
              const float* __restrict__ beta) {
  int bo = blockIdx.x;
  int o = bo & (COUT - 1);
  const float inv = 1.f / (float)(BB * NPTS);
  float mean = sums1[o] * inv;
  float var = sums2[o] * inv - mean * mean;
  float scale = gamma[o] * rsqrtf(var + BN_EPS);
  float shift = beta[o] - mean * scale;
  float4* p = (float4*)(out + (size_t)bo * NPTS);
  for (int i = threadIdx.x; i < NPTS / 4; i += blockDim.x) {
    float4 v = p[i];
    v.x = fmaxf(fmaf(v.x, scale, shift), 0.f);
    v.y = fmaxf(fmaf(v.y, scale, shift), 0.f);
    v.z = fmaxf(fmaf(v.z, scale, shift), 0.f);
    v.w = fmaxf(fmaf(v.w, scale, shift), 0.f);
    p[i] = v;
  }
}

// ---------------------------------------------------------------- launch
extern "C" void kernel_launch(void* const* d_in, const int* in_sizes, int n_in,
                              void* d_out, int out_size, void* d_ws, size_t ws_size,
                              hipStream_t stream) {
  const float* x      = (const float*)d_in[0];
  const float* coords = (const float*)d_in[1];
  const float* rot    = (const float*)d_in[2];
  const float* dist   = (const float*)d_in[3];
  const float* W      = (const float*)d_in[4];
  const float* bias   = (const float*)d_in[5];
  const float* gamma  = (const float*)d_in[6];
  const float* beta   = (const float*)d_in[7];
  float* out = (float*)d_out;

  float* ws    = (float*)d_ws;
  float* sums1 = ws;                    // 256
  float* sums2 = ws + 256;              // 256
  short* Wa    = (short*)(ws + 512);    // 72*8192 bf16

  pre_kernel<<<2305, 256, 0, stream>>>(W, Wa, sums1);
  conv_mfma<<<512, 256, 0, stream>>>(x, coords, rot, dist, Wa, bias, out, sums1, sums2);
  bn_apply<<<BB * COUT, 256, 0, stream>>>(out, sums1, sums2, gamma, beta);
}

// Round 5
// 276.253 us; speedup vs baseline: 1.4268x; 1.4268x over previous
//
#include <hip/hip_runtime.h>

#define KTAPS 9
#define DIL 6
#define BN_EPS 1e-5f
#define BB 8
#define CIN 256
#define COUT 256
#define NPTS 8192
#define BN 128
#define BSTRIDE 40   // B_lds row stride (elems)
#define XW 192       // x window cols per c8 (covers BN + 2*24 halo)
#define XOFF 32      // window col 0 = n0 - XOFF

typedef __attribute__((ext_vector_type(8))) short short8;
typedef __attribute__((ext_vector_type(4))) float f32x4;

__device__ __forceinline__ unsigned short f2bf(float f) {
  union { float f; unsigned u; } v; v.f = f;
  unsigned r = v.u + 0x7fffu + ((v.u >> 16) & 1u);   // RNE
  return (unsigned short)(r >> 16);
}

__device__ __forceinline__ void async16(const void* gp, void* lp) {
  __builtin_amdgcn_global_load_lds(
      (const __attribute__((address_space(1))) unsigned int*)gp,
      (__attribute__((address_space(3))) unsigned int*)lp, 16, 0, 0);
}

// ---------------------------------------------------------------- pre: pack W + zero sums
// Wa[chunk][mi][kk]; chunk = ktap*8 + c8; element = W[mi][c8*32+kk][ktap]
__global__ __launch_bounds__(256)
void pre_kernel(const float* __restrict__ W, short* __restrict__ Wa,
                float* __restrict__ sums) {
  int bid = blockIdx.x;
  if (bid < 2304) {
    int idx = bid * 256 + threadIdx.x;
    int kk = idx & 31;
    int mi = (idx >> 5) & 255;
    int chunk = idx >> 13;
    int ktap = chunk >> 3;
    int c = ((chunk & 7) << 5) + kk;
    Wa[idx] = (short)f2bf(W[(size_t)mi * (CIN * KTAPS) + c * KTAPS + ktap]);
  } else {
    if (threadIdx.x < 512) sums[threadIdx.x] = 0.f;
  }
}

// ---------------------------------------------------------------- MFMA conv, k-reuse via x-window LDS
__global__ __launch_bounds__(256, 2)
void conv_mfma(const float* __restrict__ x, const float* __restrict__ coords,
               const float* __restrict__ rot, const float* __restrict__ dist,
               const short* __restrict__ Wa, const float* __restrict__ bias,
               float* __restrict__ out,
               float* __restrict__ sums1, float* __restrict__ sums2) {
  __shared__ short A_lds[2][256 * 32];    // 32 KB  [m][kk] dbuf
  __shared__ short B_lds[2][BN * BSTRIDE];// 20 KB  [n][kk] dbuf
  __shared__ float x_win[32][XW];         // 24 KB  x window for current c8

  const int tid = threadIdx.x;
  const int b = blockIdx.y;
  const int n0 = blockIdx.x * BN;
  const int wave = tid >> 6;
  const int lane = tid & 63;
  const int col = lane & 15;
  const int quad = lane >> 4;
  const int tl = tid & 63;          // n-pair index for B-build (n = 2tl, 2tl+1)
  const int tkk = (tid >> 6) * 8;   // kk base for B-build

  // ---- prologue: per-thread tap weights g[k][i] for n = n0+2tl+i
  float greg[KTAPS][2];
  {
    const float* cb = coords + (size_t)b * 3 * NPTS;
    const float* rb = rot + (size_t)b * 3 * NPTS;
    const float* db = dist + (size_t)b * NPTS;
#pragma unroll
    for (int i = 0; i < 2; ++i) {
      int n = n0 + 2 * tl + i;
      float c0x = cb[n], c0y = cb[NPTS + n], c0z = cb[2 * NPTS + n];
      float r0x = rb[n], r0y = rb[NPTS + n], r0z = rb[2 * NPTS + n];
      float d0 = db[n];
      float r0n = r0x * r0x + r0y * r0y + r0z * r0z;
#pragma unroll
      for (int k = 0; k < KTAPS; ++k) {
        int j = n + (k - KTAPS / 2) * DIL;
        float gv = 0.f;
        if (j >= 0 && j < NPTS) {
          float dcx = c0x - cb[j], dcy = c0y - cb[NPTS + j], dcz = c0z - cb[2 * NPTS + j];
          float dc = dcx * dcx + dcy * dcy + dcz * dcz;
          float dd = d0 - db[j];
          dd *= dd;
          float gauss = expf(-(dc + dd) * 0.5f);
          float rjx = rb[j], rjy = rb[NPTS + j], rjz = rb[2 * NPTS + j];
          float num = r0x * rjx + r0y * rjy + r0z * rjz;
          float den = sqrtf(r0n * (rjx * rjx + rjy * rjy + rjz * rjz)) + 1e-8f;
          gv = gauss * fabsf(num / den);
        }
        greg[k][i] = gv;
      }
    }
  }

  f32x4 acc[4][8];
#pragma unroll
  for (int m = 0; m < 4; ++m)
#pragma unroll
    for (int j = 0; j < 8; ++j) acc[m][j] = (f32x4)0.f;

  const float* xb = x + (size_t)b * CIN * NPTS;
  const int xchl = tid >> 3;        // x-stage channel 0..31
  const int xc0 = (tid & 7) * 4;    // x-stage col base

  for (int c8 = 0; c8 < 8; ++c8) {
    const int cpar = c8 & 1;        // tap-buffer parity base: t = c8*9+k -> t&1 = (c8+k)&1

    // ---- stage x window for this c8 (global -> LDS, read-once)
    {
      const float* xrow = xb + (size_t)(c8 * 32 + xchl) * NPTS;
#pragma unroll
      for (int q = 0; q < 6; ++q) {
        int cw = xc0 + q * 32;
        int jg = n0 - XOFF + cw;
        float4 v;
        if (jg >= 0 && jg + 3 < NPTS) {
          v = *(const float4*)&xrow[jg];
        } else {
          float* e = (float*)&v;
#pragma unroll
          for (int u = 0; u < 4; ++u) {
            int jj = jg + u;
            e[u] = (jj >= 0 && jj < NPTS) ? xrow[jj] : 0.f;
          }
        }
        *(float4*)&x_win[xchl][cw] = v;
      }
    }
    // ---- A-DMA for tap k=0 of this c8 (chunk = c8) into buf cpar
    {
      const short* wsrc = Wa + (size_t)c8 * 8192 + tid * 8;
#pragma unroll
      for (int t4 = 0; t4 < 4; ++t4)
        async16(wsrc + t4 * 2048, &A_lds[cpar][tid * 8 + t4 * 2048]);
    }
    __syncthreads();   // x_win + A[cpar] ready

    // ---- B-build k=0 into buf cpar
    {
      const int base = 2 * tl + (0 - 4) * DIL + XOFF;
      short8 p0, p1;
#pragma unroll
      for (int cc = 0; cc < 8; ++cc) {
        float2 v = *(const float2*)&x_win[tkk + cc][base];
        p0[cc] = (short)f2bf(v.x * greg[0][0]);
        p1[cc] = (short)f2bf(v.y * greg[0][1]);
      }
      *(short8*)&B_lds[cpar][(2 * tl) * BSTRIDE + tkk] = p0;
      *(short8*)&B_lds[cpar][(2 * tl + 1) * BSTRIDE + tkk] = p1;
    }
    __syncthreads();   // B[cpar] ready

#pragma unroll
    for (int k = 0; k < KTAPS; ++k) {
      const int cur = (cpar + k) & 1;
      const int nxt = cur ^ 1;

      // ---- prefetch tap k+1: A via DMA, B built from x_win (LDS-local)
      if (k < 8) {
        const short* wsrc = Wa + (size_t)((k + 1) * 8 + c8) * 8192 + tid * 8;
#pragma unroll
        for (int t4 = 0; t4 < 4; ++t4)
          async16(wsrc + t4 * 2048, &A_lds[nxt][tid * 8 + t4 * 2048]);
        const int base = 2 * tl + ((k + 1) - 4) * DIL + XOFF;
        short8 p0, p1;
#pragma unroll
        for (int cc = 0; cc < 8; ++cc) {
          float2 v = *(const float2*)&x_win[tkk + cc][base];
          p0[cc] = (short)f2bf(v.x * greg[k + 1][0]);
          p1[cc] = (short)f2bf(v.y * greg[k + 1][1]);
        }
        *(short8*)&B_lds[nxt][(2 * tl) * BSTRIDE + tkk] = p0;
        *(short8*)&B_lds[nxt][(2 * tl + 1) * BSTRIDE + tkk] = p1;
      }

      // ---- MFMA on buf cur
      short8 af[4];
#pragma unroll
      for (int m = 0; m < 4; ++m)
        af[m] = *(short8*)&A_lds[cur][(wave * 64 + m * 16 + col) * 32 + quad * 8];
#pragma unroll
      for (int j = 0; j < 8; ++j) {
        short8 bfv = *(short8*)&B_lds[cur][(j * 16 + col) * BSTRIDE + quad * 8];
#pragma unroll
        for (int m = 0; m < 4; ++m)
          acc[m][j] = __builtin_amdgcn_mfma_f32_16x16x32_bf16(af[m], bfv, acc[m][j], 0, 0, 0);
      }
      __syncthreads();
    }
  }

  // ---- epilogue: bias, BN partial sums, store (R3-verified)
  const int obase = wave * 64;
  float* outp = out + (size_t)b * COUT * NPTS + n0;
#pragma unroll
  for (int m = 0; m < 4; ++m) {
    const int o0 = obase + m * 16 + quad * 4;
    const float4 bv = *(const float4*)&bias[o0];
#pragma unroll
    for (int j = 0; j < 8; ++j) {
      acc[m][j][0] += bv.x; acc[m][j][1] += bv.y;
      acc[m][j][2] += bv.z; acc[m][j][3] += bv.w;
    }
#pragma unroll
    for (int r = 0; r < 4; ++r) {
      float s1 = 0.f, s2 = 0.f;
#pragma unroll
      for (int j = 0; j < 8; ++j) {
        float v = acc[m][j][r];
        s1 += v; s2 += v * v;
      }
      s1 += __shfl_xor(s1, 1); s2 += __shfl_xor(s2, 1);
      s1 += __shfl_xor(s1, 2); s2 += __shfl_xor(s2, 2);
      s1 += __shfl_xor(s1, 4); s2 += __shfl_xor(s2, 4);
      s1 += __shfl_xor(s1, 8); s2 += __shfl_xor(s2, 8);
      if (col == 0) {
        atomicAdd(&sums1[o0 + r], s1);
        atomicAdd(&sums2[o0 + r], s2);
      }
#pragma unroll
      for (int j = 0; j < 8; ++j)
        outp[(size_t)(o0 + r) * NPTS + j * 16 + col] = acc[m][j][r];
    }
  }
}

// ---------------------------------------------------------------- BN + ReLU
__global__ __launch_bounds__(256)
void bn_apply(float* __restrict__ out, const float* __restrict__ sums1,
              const float* __restrict__ sums2, const float* __restrict__ gamma,
              const float* __restrict__ beta) {
  int bo = blockIdx.x;
  int o = bo & (COUT - 1);
  const float inv = 1.f / (float)(BB * NPTS);
  float mean = sums1[o] * inv;
  float var = sums2[o] * inv - mean * mean;
  float scale = gamma[o] * rsqrtf(var + BN_EPS);
  float shift = beta[o] - mean * scale;
  float4* p = (float4*)(out + (size_t)bo * NPTS);
  for (int i = threadIdx.x; i < NPTS / 4; i += blockDim.x) {
    float4 v = p[i];
    v.x = fmaxf(fmaf(v.x, scale, shift), 0.f);
    v.y = fmaxf(fmaf(v.y, scale, shift), 0.f);
    v.z = fmaxf(fmaf(v.z, scale, shift), 0.f);
    v.w = fmaxf(fmaf(v.w, scale, shift), 0.f);
    p[i] = v;
  }
}

// ---------------------------------------------------------------- launch
extern "C" void kernel_launch(void* const* d_in, const int* in_sizes, int n_in,
                              void* d_out, int out_size, void* d_ws, size_t ws_size,
                              hipStream_t stream) {
  const float* x      = (const float*)d_in[0];
  const float* coords = (const float*)d_in[1];
  const float* rot    = (const float*)d_in[2];
  const float* dist   = (const float*)d_in[3];
  const float* W      = (const float*)d_in[4];
  const float* bias   = (const float*)d_in[5];
  const float* gamma  = (const float*)d_in[6];
  const float* beta   = (const float*)d_in[7];
  float* out = (float*)d_out;

  float* ws    = (float*)d_ws;
  float* sums1 = ws;                    // 256
  float* sums2 = ws + 256;              // 256
  short* Wa    = (short*)(ws + 512);    // 72*8192 bf16

  pre_kernel<<<2305, 256, 0, stream>>>(W, Wa, sums1);
  conv_mfma<<<dim3(NPTS / BN, BB), 256, 0, stream>>>(x, coords, rot, dist, Wa, bias, out, sums1, sums2);
  bn_apply<<<BB * COUT, 256, 0, stream>>>(out, sums1, sums2, gamma, beta);
}